// Round 20
// baseline (411.569 us; speedup 1.0000x reference)
//
#include <hip/hip_runtime.h>

#define NN 50000
#define EE 800000
#define NT32 1563    // ceil(NN/32)
#define NTILE 3125   // NN/16 (pooled tiles)
#define NSB 196      // scan blocks: 196*256 = 50176 >= NN
#define MAXSLAB 1024

#define OUT_S1 4
#define OUT_A1 (4 + NN * 64)
#define OUT_S2 (OUT_A1 + 64 * 64)
#define OUT_ADJ2 (OUT_S2 + 64 * 16)

__device__ __forceinline__ float block_sum256(float v, float* red) {
  v += __shfl_xor(v, 32); v += __shfl_xor(v, 16); v += __shfl_xor(v, 8);
  v += __shfl_xor(v, 4);  v += __shfl_xor(v, 2);  v += __shfl_xor(v, 1);
  __syncthreads();
  if ((threadIdx.x & 63) == 0) red[threadIdx.x >> 6] = v;
  __syncthreads();
  return red[0] + red[1] + red[2] + red[3];
}

// ---- MLP-unrolled gather: sum rows[csr[off..off+c)] (64-float rows),
//      16 lanes per node, lane l holds floats [l*4, l*4+4).
__device__ __forceinline__ float4 gather_rows64(
    const float* __restrict__ rows, const int* __restrict__ csr,
    int off, int c, int l, int g) {
  float4 a0 = make_float4(0.f, 0.f, 0.f, 0.f);
  float4 a1 = a0, a2 = a0, a3 = a0;
  int bb = 0;
  for (; bb + 16 <= c; bb += 16) {
    int myid = csr[off + bb + l];
    #pragma unroll
    for (int j = 0; j < 16; j += 4) {
      int s0 = __shfl(myid, g + j + 0, 64);
      int s1 = __shfl(myid, g + j + 1, 64);
      int s2 = __shfl(myid, g + j + 2, 64);
      int s3 = __shfl(myid, g + j + 3, 64);
      const float4 v0 = *(const float4*)&rows[(size_t)s0 * 64 + l * 4];
      const float4 v1 = *(const float4*)&rows[(size_t)s1 * 64 + l * 4];
      const float4 v2 = *(const float4*)&rows[(size_t)s2 * 64 + l * 4];
      const float4 v3 = *(const float4*)&rows[(size_t)s3 * 64 + l * 4];
      a0.x += v0.x; a0.y += v0.y; a0.z += v0.z; a0.w += v0.w;
      a1.x += v1.x; a1.y += v1.y; a1.z += v1.z; a1.w += v1.w;
      a2.x += v2.x; a2.y += v2.y; a2.z += v2.z; a2.w += v2.w;
      a3.x += v3.x; a3.y += v3.y; a3.z += v3.z; a3.w += v3.w;
    }
  }
  int m = c - bb;
  if (m > 0) {
    int myid = (l < m) ? csr[off + bb + l] : 0;
    int j = 0;
    for (; j + 2 <= m; j += 2) {
      int s0 = __shfl(myid, g + j + 0, 64);
      int s1 = __shfl(myid, g + j + 1, 64);
      const float4 v0 = *(const float4*)&rows[(size_t)s0 * 64 + l * 4];
      const float4 v1 = *(const float4*)&rows[(size_t)s1 * 64 + l * 4];
      a0.x += v0.x; a0.y += v0.y; a0.z += v0.z; a0.w += v0.w;
      a1.x += v1.x; a1.y += v1.y; a1.z += v1.z; a1.w += v1.w;
    }
    if (j < m) {
      int s0 = __shfl(myid, g + j, 64);
      const float4 v0 = *(const float4*)&rows[(size_t)s0 * 64 + l * 4];
      a2.x += v0.x; a2.y += v0.y; a2.z += v0.z; a2.w += v0.w;
    }
  }
  a0.x += a1.x; a0.y += a1.y; a0.z += a1.z; a0.w += a1.w;
  a2.x += a3.x; a2.y += a3.y; a2.z += a3.z; a2.w += a3.w;
  a0.x += a2.x; a0.y += a2.y; a0.z += a2.z; a0.w += a2.w;
  return a0;
}

// ---- gather + sum-of-squares of every loaded element (for mincut_den)
__device__ __forceinline__ float4 gather_rows64_sq(
    const float* __restrict__ rows, const int* __restrict__ csr,
    int off, int c, int l, int g, float& dsq) {
  float4 a0 = make_float4(0.f, 0.f, 0.f, 0.f);
  float4 a1 = a0, a2 = a0, a3 = a0;
  int bb = 0;
  for (; bb + 16 <= c; bb += 16) {
    int myid = csr[off + bb + l];
    #pragma unroll
    for (int j = 0; j < 16; j += 4) {
      int s0 = __shfl(myid, g + j + 0, 64);
      int s1 = __shfl(myid, g + j + 1, 64);
      int s2 = __shfl(myid, g + j + 2, 64);
      int s3 = __shfl(myid, g + j + 3, 64);
      const float4 v0 = *(const float4*)&rows[(size_t)s0 * 64 + l * 4];
      const float4 v1 = *(const float4*)&rows[(size_t)s1 * 64 + l * 4];
      const float4 v2 = *(const float4*)&rows[(size_t)s2 * 64 + l * 4];
      const float4 v3 = *(const float4*)&rows[(size_t)s3 * 64 + l * 4];
      a0.x += v0.x; a0.y += v0.y; a0.z += v0.z; a0.w += v0.w;
      a1.x += v1.x; a1.y += v1.y; a1.z += v1.z; a1.w += v1.w;
      a2.x += v2.x; a2.y += v2.y; a2.z += v2.z; a2.w += v2.w;
      a3.x += v3.x; a3.y += v3.y; a3.z += v3.z; a3.w += v3.w;
      dsq += v0.x * v0.x + v0.y * v0.y + v0.z * v0.z + v0.w * v0.w;
      dsq += v1.x * v1.x + v1.y * v1.y + v1.z * v1.z + v1.w * v1.w;
      dsq += v2.x * v2.x + v2.y * v2.y + v2.z * v2.z + v2.w * v2.w;
      dsq += v3.x * v3.x + v3.y * v3.y + v3.z * v3.z + v3.w * v3.w;
    }
  }
  int m = c - bb;
  if (m > 0) {
    int myid = (l < m) ? csr[off + bb + l] : 0;
    int j = 0;
    for (; j + 2 <= m; j += 2) {
      int s0 = __shfl(myid, g + j + 0, 64);
      int s1 = __shfl(myid, g + j + 1, 64);
      const float4 v0 = *(const float4*)&rows[(size_t)s0 * 64 + l * 4];
      const float4 v1 = *(const float4*)&rows[(size_t)s1 * 64 + l * 4];
      a0.x += v0.x; a0.y += v0.y; a0.z += v0.z; a0.w += v0.w;
      a1.x += v1.x; a1.y += v1.y; a1.z += v1.z; a1.w += v1.w;
      dsq += v0.x * v0.x + v0.y * v0.y + v0.z * v0.z + v0.w * v0.w;
      dsq += v1.x * v1.x + v1.y * v1.y + v1.z * v1.z + v1.w * v1.w;
    }
    if (j < m) {
      int s0 = __shfl(myid, g + j, 64);
      const float4 v0 = *(const float4*)&rows[(size_t)s0 * 64 + l * 4];
      a2.x += v0.x; a2.y += v0.y; a2.z += v0.z; a2.w += v0.w;
      dsq += v0.x * v0.x + v0.y * v0.y + v0.z * v0.z + v0.w * v0.w;
    }
  }
  a0.x += a1.x; a0.y += a1.y; a0.z += a1.z; a0.w += a1.w;
  a2.x += a3.x; a2.y += a3.y; a2.z += a3.z; a2.w += a3.w;
  a0.x += a2.x; a0.y += a2.y; a0.z += a2.z; a0.w += a2.w;
  return a0;
}

// ---- H: histogram in-degree (by dst, for CSR) only
__global__ __launch_bounds__(256) void k_hist(
    const int* __restrict__ ei, int* __restrict__ cnt_dst) {
  int e = blockIdx.x * 256 + threadIdx.x;
  int d = ei[EE + e];
  atomicAdd(&cnt_dst[d], 1);
}

// ---- Scan stage 1: per-block exclusive scan -> cursor (local), block sums
__global__ __launch_bounds__(256) void k_scan1(
    const int* __restrict__ cnt, int* __restrict__ cursor, int* __restrict__ bsum) {
  __shared__ int sh[256];
  int t = threadIdx.x;
  int idx = blockIdx.x * 256 + t;
  int v = (idx < NN) ? cnt[idx] : 0;
  sh[t] = v;
  __syncthreads();
  for (int o = 1; o < 256; o <<= 1) {
    int u = (t >= o) ? sh[t - o] : 0;
    __syncthreads();
    sh[t] += u;
    __syncthreads();
  }
  if (idx < NN) cursor[idx] = sh[t] - v;
  if (t == 255) bsum[blockIdx.x] = sh[255];
}

// ---- Scan stage 2: exclusive scan of block sums (1 block); also zero den
__global__ __launch_bounds__(256) void k_scan2(
    int* __restrict__ bsum, float* __restrict__ den) {
  __shared__ int sh[256];
  int t = threadIdx.x;
  int v = (t < NSB) ? bsum[t] : 0;
  sh[t] = v;
  __syncthreads();
  for (int o = 1; o < 256; o <<= 1) {
    int u = (t >= o) ? sh[t - o] : 0;
    __syncthreads();
    sh[t] += u;
    __syncthreads();
  }
  if (t < NSB) bsum[t] = sh[t] - v;
  if (t == 0) den[0] = 0.f;
}

// ---- F: fill CSR (cursor holds LOCAL prefix; add bsum inline).
__global__ __launch_bounds__(256) void k_fill(
    const int* __restrict__ ei, int* __restrict__ cursor,
    const int* __restrict__ bsum, int* __restrict__ csr) {
  int e = blockIdx.x * 256 + threadIdx.x;
  int s = ei[e], d = ei[EE + e];
  int pos = atomicAdd(&cursor[d], 1) + bsum[d >> 8];
  csr[pos] = s;
}

// ---- FUSED1 (32-node tiles, LDS-union):
//      A: gather agg + stage x; B: x1 (regs) -> global + smem; C: s1 LN+softmax.
__global__ __launch_bounds__(256, 4) void k_fused1(
    const float* __restrict__ x, const int* __restrict__ csr,
    const int* __restrict__ cur_end, const int* __restrict__ cnt,
    const int* __restrict__ bsum,
    const float* __restrict__ W1rel, const float* __restrict__ b1,
    const float* __restrict__ W1root,
    const float* __restrict__ Wp1, const float* __restrict__ bp1,
    const float* __restrict__ lnw, const float* __restrict__ lnb,
    float* __restrict__ x1, float* __restrict__ s1_out,
    float* __restrict__ s1s) {
  __shared__ float smem[4224];   // A/B: agg=[0,2048) x=[2048,4096); C: x1 32x132
  float* agg_t = smem;
  float* x_t   = smem + 2048;
  float* x1_t  = smem;           // [n][k] at n*132+k (padded rows)
  int t = threadIdx.x;
  int base = blockIdx.x * 32;

  // ---- Phase A
  {
    int n16 = t >> 4, l = t & 15;
    #pragma unroll
    for (int half = 0; half < 2; ++half) {
      int n = n16 + half * 16;
      int node = base + n;
      if (node < NN) {
        *(float4*)&x_t[n * 64 + l * 4] = *(const float4*)&x[(size_t)node * 64 + l * 4];
        int c = cnt[node];
        int off = cur_end[node] - c + bsum[node >> 8];
        float4 acc = gather_rows64(x, csr, off, c, l, t & 48);
        *(float4*)&agg_t[n * 64 + l * 4] = acc;
      } else {
        float4 z = make_float4(0.f, 0.f, 0.f, 0.f);
        *(float4*)&x_t[n * 64 + l * 4] = z;
        *(float4*)&agg_t[n * 64 + l * 4] = z;
      }
    }
  }
  __syncthreads();

  // ---- Phase B: x1 tile in registers. thread = 4 rows x 4 cols.
  int rg = t >> 5, cg = t & 31;
  int r0 = rg * 4;
  int c4 = cg * 4;
  float4 r0v, r1v, r2v, r3v;
  {
    float4 acc0 = *(const float4*)&b1[c4];
    float4 acc1 = acc0, acc2 = acc0, acc3 = acc0;
    #pragma unroll 4
    for (int k = 0; k < 64; ++k) {
      const float4 w1 = *(const float4*)&W1rel[k * 128 + c4];
      const float4 w2 = *(const float4*)&W1root[k * 128 + c4];
      float a0 = agg_t[(r0 + 0) * 64 + k], e0 = x_t[(r0 + 0) * 64 + k];
      float a1 = agg_t[(r0 + 1) * 64 + k], e1 = x_t[(r0 + 1) * 64 + k];
      float a2 = agg_t[(r0 + 2) * 64 + k], e2 = x_t[(r0 + 2) * 64 + k];
      float a3 = agg_t[(r0 + 3) * 64 + k], e3 = x_t[(r0 + 3) * 64 + k];
      acc0.x += a0 * w1.x + e0 * w2.x; acc0.y += a0 * w1.y + e0 * w2.y;
      acc0.z += a0 * w1.z + e0 * w2.z; acc0.w += a0 * w1.w + e0 * w2.w;
      acc1.x += a1 * w1.x + e1 * w2.x; acc1.y += a1 * w1.y + e1 * w2.y;
      acc1.z += a1 * w1.z + e1 * w2.z; acc1.w += a1 * w1.w + e1 * w2.w;
      acc2.x += a2 * w1.x + e2 * w2.x; acc2.y += a2 * w1.y + e2 * w2.y;
      acc2.z += a2 * w1.z + e2 * w2.z; acc2.w += a2 * w1.w + e2 * w2.w;
      acc3.x += a3 * w1.x + e3 * w2.x; acc3.y += a3 * w1.y + e3 * w2.y;
      acc3.z += a3 * w1.z + e3 * w2.z; acc3.w += a3 * w1.w + e3 * w2.w;
    }
    r0v.x = fmaxf(acc0.x, 0.f); r0v.y = fmaxf(acc0.y, 0.f);
    r0v.z = fmaxf(acc0.z, 0.f); r0v.w = fmaxf(acc0.w, 0.f);
    r1v.x = fmaxf(acc1.x, 0.f); r1v.y = fmaxf(acc1.y, 0.f);
    r1v.z = fmaxf(acc1.z, 0.f); r1v.w = fmaxf(acc1.w, 0.f);
    r2v.x = fmaxf(acc2.x, 0.f); r2v.y = fmaxf(acc2.y, 0.f);
    r2v.z = fmaxf(acc2.z, 0.f); r2v.w = fmaxf(acc2.w, 0.f);
    r3v.x = fmaxf(acc3.x, 0.f); r3v.y = fmaxf(acc3.y, 0.f);
    r3v.z = fmaxf(acc3.z, 0.f); r3v.w = fmaxf(acc3.w, 0.f);
    if (base + r0 + 3 < NN) {
      *(float4*)&x1[(size_t)(base + r0 + 0) * 128 + c4] = r0v;
      *(float4*)&x1[(size_t)(base + r0 + 1) * 128 + c4] = r1v;
      *(float4*)&x1[(size_t)(base + r0 + 2) * 128 + c4] = r2v;
      *(float4*)&x1[(size_t)(base + r0 + 3) * 128 + c4] = r3v;
    } else {
      if (base + r0 + 0 < NN) *(float4*)&x1[(size_t)(base + r0 + 0) * 128 + c4] = r0v;
      if (base + r0 + 1 < NN) *(float4*)&x1[(size_t)(base + r0 + 1) * 128 + c4] = r1v;
      if (base + r0 + 2 < NN) *(float4*)&x1[(size_t)(base + r0 + 2) * 128 + c4] = r2v;
    }
  }
  __syncthreads();  // all reads of agg_t/x_t complete
  *(float4*)&x1_t[(r0 + 0) * 132 + c4] = r0v;
  *(float4*)&x1_t[(r0 + 1) * 132 + c4] = r1v;
  *(float4*)&x1_t[(r0 + 2) * 132 + c4] = r2v;
  *(float4*)&x1_t[(r0 + 3) * 132 + c4] = r3v;
  __syncthreads();

  // ---- Phase C: thread = 4 rows x 2 cols, k-blocked x4, unroll pinned.
  {
    int c2 = cg * 2;
    const float2 b0 = *(const float2*)&bp1[c2];
    float2 acc0 = b0, acc1 = b0, acc2 = b0, acc3 = b0;
    #pragma unroll 4
    for (int k0 = 0; k0 < 128; k0 += 4) {
      const float2 w0 = *(const float2*)&Wp1[(k0 + 0) * 64 + c2];
      const float2 w1 = *(const float2*)&Wp1[(k0 + 1) * 64 + c2];
      const float2 w2 = *(const float2*)&Wp1[(k0 + 2) * 64 + c2];
      const float2 w3 = *(const float2*)&Wp1[(k0 + 3) * 64 + c2];
      const float4 x0 = *(const float4*)&x1_t[(r0 + 0) * 132 + k0];
      const float4 x1v = *(const float4*)&x1_t[(r0 + 1) * 132 + k0];
      const float4 x2v = *(const float4*)&x1_t[(r0 + 2) * 132 + k0];
      const float4 x3v = *(const float4*)&x1_t[(r0 + 3) * 132 + k0];
      acc0.x += x0.x * w0.x + x0.y * w1.x + x0.z * w2.x + x0.w * w3.x;
      acc0.y += x0.x * w0.y + x0.y * w1.y + x0.z * w2.y + x0.w * w3.y;
      acc1.x += x1v.x * w0.x + x1v.y * w1.x + x1v.z * w2.x + x1v.w * w3.x;
      acc1.y += x1v.x * w0.y + x1v.y * w1.y + x1v.z * w2.y + x1v.w * w3.y;
      acc2.x += x2v.x * w0.x + x2v.y * w1.x + x2v.z * w2.x + x2v.w * w3.x;
      acc2.y += x2v.x * w0.y + x2v.y * w1.y + x2v.z * w2.y + x2v.w * w3.y;
      acc3.x += x3v.x * w0.x + x3v.y * w1.x + x3v.z * w2.x + x3v.w * w3.x;
      acc3.y += x3v.x * w0.y + x3v.y * w1.y + x3v.z * w2.y + x3v.w * w3.y;
    }
    const float2 lw = *(const float2*)&lnw[c2];
    const float2 lb = *(const float2*)&lnb[c2];
    float2 accs[4] = {acc0, acc1, acc2, acc3};
    #pragma unroll
    for (int i = 0; i < 4; ++i) {
      int row = base + r0 + i;
      float ax = accs[i].x, ay = accs[i].y;
      float m = ax + ay;
      m += __shfl_xor(m, 1); m += __shfl_xor(m, 2); m += __shfl_xor(m, 4);
      m += __shfl_xor(m, 8); m += __shfl_xor(m, 16);
      m *= (1.0f / 64.0f);
      float dx = ax - m, dy = ay - m;
      float v = dx * dx + dy * dy;
      v += __shfl_xor(v, 1); v += __shfl_xor(v, 2); v += __shfl_xor(v, 4);
      v += __shfl_xor(v, 8); v += __shfl_xor(v, 16);
      v *= (1.0f / 64.0f);
      float rstd = rsqrtf(v + 1e-5f);
      float lnx = dx * rstd * lw.x + lb.x;
      float lny = dy * rstd * lw.y + lb.y;
      float mx = fmaxf(lnx, lny);
      mx = fmaxf(mx, __shfl_xor(mx, 1)); mx = fmaxf(mx, __shfl_xor(mx, 2));
      mx = fmaxf(mx, __shfl_xor(mx, 4)); mx = fmaxf(mx, __shfl_xor(mx, 8));
      mx = fmaxf(mx, __shfl_xor(mx, 16));
      float ex = expf(lnx - mx), ey = expf(lny - mx);
      float se = ex + ey;
      se += __shfl_xor(se, 1); se += __shfl_xor(se, 2); se += __shfl_xor(se, 4);
      se += __shfl_xor(se, 8); se += __shfl_xor(se, 16);
      float inv = 1.0f / se;
      ex *= inv; ey *= inv;
      if (row < NN) {
        *(float2*)&s1_out[(size_t)row * 64 + c2] = make_float2(lnx, lny);
        *(float2*)&s1s[(size_t)row * 64 + c2] = make_float2(ex, ey);
      }
    }
  }
}

// ---- POOLED_ALL: per 16-node tile (grid-stride): stage s,x1; gather G (+den);
//      px += s.T@x1, padj += G.T@s, sts += s.T@s. Slab: [px 8192|padj 4096|sts 4096]
__global__ __launch_bounds__(256, 4) void k_pooled_all(
    const float* __restrict__ s1s, const float* __restrict__ x1,
    const int* __restrict__ csr, const int* __restrict__ cur_end,
    const int* __restrict__ cnt, const int* __restrict__ bsum,
    float* __restrict__ part, float* __restrict__ den) {
  __shared__ float s_t[1024];   // 16 x 64
  __shared__ float g_t[1024];   // 16 x 64
  __shared__ float x_t[2048];   // 16 x 128
  __shared__ float red[4];
  int t = threadIdx.x;
  int kg = t >> 5;              // 0..7 : k = kg*8 + j
  int cg = t & 31;              // 0..31
  int c1 = cg * 4;              // x cols
  int cc = (cg & 15) * 4;       // s cols (padj for cg<16, sts for cg>=16)
  bool is_padj = (cg < 16);
  float a1[8][4], a2[8][4];
  float dsq = 0.f;
  #pragma unroll
  for (int j = 0; j < 8; ++j)
    #pragma unroll
    for (int q = 0; q < 4; ++q) { a1[j][q] = 0.f; a2[j][q] = 0.f; }

  for (int tile = blockIdx.x; tile < NTILE; tile += gridDim.x) {
    size_t base = (size_t)tile * 16;
    __syncthreads();
    *(float4*)&s_t[t * 4] = *(const float4*)&s1s[base * 64 + t * 4];
    *(float4*)&x_t[t * 8] = *(const float4*)&x1[base * 128 + t * 8];
    *(float4*)&x_t[t * 8 + 4] = *(const float4*)&x1[base * 128 + t * 8 + 4];
    {
      int n16 = t >> 4, l = t & 15;
      int node = (int)base + n16;
      int c = cnt[node];
      int off = cur_end[node] - c + bsum[node >> 8];
      float4 acc = gather_rows64_sq(s1s, csr, off, c, l, t & 48, dsq);
      *(float4*)&g_t[n16 * 64 + l * 4] = acc;
    }
    __syncthreads();
    #pragma unroll 2
    for (int r = 0; r < 16; ++r) {
      const float4 xv = *(const float4*)&x_t[r * 128 + c1];
      const float4 sv = *(const float4*)&s_t[r * 64 + cc];
      const float4 k0 = *(const float4*)&s_t[r * 64 + kg * 8];
      const float4 k1 = *(const float4*)&s_t[r * 64 + kg * 8 + 4];
      const float4 g0 = *(const float4*)&g_t[r * 64 + kg * 8];
      const float4 g1 = *(const float4*)&g_t[r * 64 + kg * 8 + 4];
      float sk[8] = {k0.x, k0.y, k0.z, k0.w, k1.x, k1.y, k1.z, k1.w};
      float gk[8] = {g0.x, g0.y, g0.z, g0.w, g1.x, g1.y, g1.z, g1.w};
      #pragma unroll
      for (int j = 0; j < 8; ++j) {
        float m2 = is_padj ? gk[j] : sk[j];
        a1[j][0] += sk[j] * xv.x; a1[j][1] += sk[j] * xv.y;
        a1[j][2] += sk[j] * xv.z; a1[j][3] += sk[j] * xv.w;
        a2[j][0] += m2 * sv.x; a2[j][1] += m2 * sv.y;
        a2[j][2] += m2 * sv.z; a2[j][3] += m2 * sv.w;
      }
    }
  }
  float* slab = part + (size_t)blockIdx.x * 16384;
  float* o2base = slab + (is_padj ? 8192 : 12288);
  #pragma unroll
  for (int j = 0; j < 8; ++j) {
    int k = kg * 8 + j;
    *(float4*)&slab[k * 128 + c1] = make_float4(a1[j][0], a1[j][1], a1[j][2], a1[j][3]);
    *(float4*)&o2base[k * 64 + cc] = make_float4(a2[j][0], a2[j][1], a2[j][2], a2[j][3]);
  }
  float dtot = block_sum256(dsq, red);
  if (t == 0) atomicAdd(den, dtot);
}

// ---- R1: partial-reduce slabs. grid = 16 i-blocks x 32 slab-groups.
__global__ __launch_bounds__(256) void k_reduce1(
    const float* __restrict__ part, int nslab, int chunk,
    float* __restrict__ part2) {
  int ib = blockIdx.x & 15;
  int bs = blockIdx.x >> 4;              // 0..31
  int i4 = ib * 256 + threadIdx.x;       // float4 index 0..4095
  int b0 = bs * chunk;
  int b1 = b0 + chunk; if (b1 > nslab) b1 = nslab;
  float4 acc = make_float4(0.f, 0.f, 0.f, 0.f);
  for (int b = b0; b < b1; ++b) {
    const float4 v = *(const float4*)&part[(size_t)b * 16384 + (size_t)i4 * 4];
    acc.x += v.x; acc.y += v.y; acc.z += v.z; acc.w += v.w;
  }
  *(float4*)&part2[(size_t)bs * 16384 + (size_t)i4 * 4] = acc;
}

// ---- R2: final reduce of 32 partials -> dst = [px 8192 | padj 4096 | sts 4096]
__global__ __launch_bounds__(256) void k_reduce2(
    const float* __restrict__ part2, float* __restrict__ dst) {
  int i = blockIdx.x * 256 + threadIdx.x;  // 0..16383
  float acc = 0.f;
  #pragma unroll
  for (int b = 0; b < 32; ++b) acc += part2[b * 16384 + i];
  dst[i] = acc;
}

// ---- P2a: mc1, o1, A1, agg2 = A1.T @ pooled_x
__global__ __launch_bounds__(256) void k_p2a(
    const float* __restrict__ padj_g, const float* __restrict__ sts_g,
    const float* __restrict__ den_g, const float* __restrict__ px_g,
    float* __restrict__ out, float* __restrict__ A1f, float* __restrict__ agg2) {
  __shared__ float padj[4096];
  __shared__ float A1s[4096];
  __shared__ float invs[64];
  __shared__ float red[4];
  int t = threadIdx.x;
  for (int i = t; i < 4096; i += 256) padj[i] = padj_g[i];
  __syncthreads();
  float num = (t < 64) ? padj[t * 64 + t] : 0.f;
  num = block_sum256(num, red);
  float n2 = 0.f;
  for (int i = t; i < 4096; i += 256) { float v = sts_g[i]; n2 += v * v; }
  n2 = block_sum256(n2, red);
  float nrm = sqrtf(n2);
  float oacc = 0.f;
  for (int i = t; i < 4096; i += 256) {
    float v = sts_g[i] / (nrm + 1e-10f);
    if ((i >> 6) == (i & 63)) v -= 0.125f;  // 1/sqrt(64)
    oacc += v * v;
  }
  oacc = block_sum256(oacc, red);
  if (t == 0) {
    out[0] = -num / (den_g[0] + 1e-10f);
    out[1] = sqrtf(oacc);
  }
  if (t < 64) {
    float rs = 0.f;
    for (int j = 0; j < 64; ++j)
      if (j != t) rs += padj[t * 64 + j];
    invs[t] = 1.0f / (sqrtf(rs) + 1e-15f);
  }
  __syncthreads();
  const float THRv = 1.0f / 63.0f;
  for (int i = t; i < 4096; i += 256) {
    int r = i >> 6, c = i & 63;
    float a = (r == c) ? 0.f : padj[i] * invs[r] * invs[c];
    float b = (a > THRv) ? 1.0f : 0.0f;
    out[OUT_A1 + i] = b;
    A1f[i] = b;
    A1s[i] = b;
  }
  __syncthreads();
  int j = t >> 2, q = t & 3;
  float acc[32];
  #pragma unroll
  for (int c = 0; c < 32; ++c) acc[c] = 0.f;
  for (int i = 0; i < 64; ++i) {
    float a = A1s[i * 64 + j];
    const float* pxr = px_g + i * 128 + q * 32;
    #pragma unroll
    for (int c = 0; c < 32; ++c) acc[c] += a * pxr[c];
  }
  #pragma unroll
  for (int c = 0; c < 32; ++c) agg2[j * 128 + q * 32 + c] = acc[c];
}

// ---- P2b: x2 = relu(agg2 @ W2_rel + b2 + pooled_x @ W2_root)
__global__ __launch_bounds__(128) void k_x2(
    const float* __restrict__ agg2, const float* __restrict__ px,
    const float* __restrict__ W2rel, const float* __restrict__ b2,
    const float* __restrict__ W2root, float* __restrict__ x2) {
  int row = blockIdx.x, col = threadIdx.x;
  const float* ar = agg2 + row * 128;
  const float* xr = px + row * 128;
  float acc = b2[col];
  #pragma unroll 4
  for (int k = 0; k < 128; ++k)
    acc += ar[k] * W2rel[k * 128 + col] + xr[k] * W2root[k * 128 + col];
  x2[row * 128 + col] = fmaxf(acc, 0.f);
}

// ---- P2c: s2 (LN), softmax, A_s2, mincut2, adj2
__global__ __launch_bounds__(256) void k_p2c(
    const float* __restrict__ x2g, const float* __restrict__ Wp2,
    const float* __restrict__ bp2, const float* __restrict__ lnw,
    const float* __restrict__ lnb, const float* __restrict__ A1f,
    float* __restrict__ out) {
  __shared__ float A1s[4096];
  __shared__ float s2lin[1024];
  __shared__ float s2s[1024];
  __shared__ float As2[1024];
  __shared__ float deg2[64];
  __shared__ float padj2[256];
  __shared__ float sts2[256];
  __shared__ float inv2[16];
  __shared__ float red[4];
  int t = threadIdx.x;
  for (int i = t; i < 4096; i += 256) A1s[i] = A1f[i];
  for (int it = 0; it < 4; ++it) {
    int idx = t + it * 256;
    int r = idx >> 4, c = idx & 15;
    float acc = bp2[c];
    const float* xr = x2g + r * 128;
    #pragma unroll 8
    for (int k = 0; k < 128; ++k) acc += xr[k] * Wp2[k * 16 + c];
    s2lin[idx] = acc;
  }
  __syncthreads();
  if (t < 64) {
    float m = 0.f;
    #pragma unroll
    for (int c = 0; c < 16; ++c) m += s2lin[t * 16 + c];
    m *= (1.0f / 16.0f);
    float v = 0.f;
    #pragma unroll
    for (int c = 0; c < 16; ++c) { float d = s2lin[t * 16 + c] - m; v += d * d; }
    v *= (1.0f / 16.0f);
    float rstd = rsqrtf(v + 1e-5f);
    float mx = -1e30f;
    float lnv[16];
    #pragma unroll
    for (int c = 0; c < 16; ++c) {
      lnv[c] = (s2lin[t * 16 + c] - m) * rstd * lnw[c] + lnb[c];
      out[OUT_S2 + t * 16 + c] = lnv[c];
      mx = fmaxf(mx, lnv[c]);
    }
    float se = 0.f;
    #pragma unroll
    for (int c = 0; c < 16; ++c) { float e = expf(lnv[c] - mx); s2s[t * 16 + c] = e; se += e; }
    float inv = 1.0f / se;
    #pragma unroll
    for (int c = 0; c < 16; ++c) s2s[t * 16 + c] *= inv;
    float dg = 0.f;
    for (int j = 0; j < 64; ++j) dg += A1s[t * 64 + j];
    deg2[t] = dg;
  }
  __syncthreads();
  for (int it = 0; it < 4; ++it) {
    int idx = t + it * 256;
    int i = idx >> 4, c = idx & 15;
    float acc = 0.f;
    for (int j = 0; j < 64; ++j) acc += A1s[i * 64 + j] * s2s[j * 16 + c];
    As2[idx] = acc;
  }
  __syncthreads();
  {
    int a = t >> 4, b = t & 15;
    float acc = 0.f, accs = 0.f;
    for (int i = 0; i < 64; ++i) {
      float sa = s2s[i * 16 + a];
      acc += sa * As2[i * 16 + b];
      accs += sa * s2s[i * 16 + b];
    }
    padj2[t] = acc;
    sts2[t] = accs;
  }
  __syncthreads();
  float num2 = (t < 16) ? padj2[t * 17] : 0.f;
  num2 = block_sum256(num2, red);
  float dpart = 0.f;
  if (t < 64) {
    float ss = 0.f;
    #pragma unroll
    for (int c = 0; c < 16; ++c) ss += s2s[t * 16 + c] * s2s[t * 16 + c];
    dpart = deg2[t] * ss;
  }
  float den2 = block_sum256(dpart, red);
  float n2 = sts2[t] * sts2[t];
  n2 = block_sum256(n2, red);
  float nrm2 = sqrtf(n2);
  float ov;
  {
    float v = sts2[t] / (nrm2 + 1e-10f);
    if ((t >> 4) == (t & 15)) v -= 0.25f;  // 1/sqrt(16)
    ov = v * v;
  }
  ov = block_sum256(ov, red);
  if (t == 0) {
    out[2] = -num2 / (den2 + 1e-10f);
    out[3] = sqrtf(ov);
  }
  if (t < 16) {
    float rs = 0.f;
    #pragma unroll
    for (int b = 0; b < 16; ++b)
      if (b != t) rs += padj2[t * 16 + b];
    inv2[t] = 1.0f / (sqrtf(rs) + 1e-15f);
  }
  __syncthreads();
  {
    int a = t >> 4, b = t & 15;
    float v = (a == b) ? 0.f : padj2[t] * inv2[a] * inv2[b];
    out[OUT_ADJ2 + t] = v;
  }
}

extern "C" void kernel_launch(void* const* d_in, const int* in_sizes, int n_in,
                              void* d_out, int out_size, void* d_ws, size_t ws_size,
                              hipStream_t stream) {
  const float* x      = (const float*)d_in[0];
  const int*   ei     = (const int*)d_in[1];
  const float* W1_rel = (const float*)d_in[2];
  const float* b1_rel = (const float*)d_in[3];
  const float* W1_root= (const float*)d_in[4];
  const float* Wp1    = (const float*)d_in[5];
  const float* bp1    = (const float*)d_in[6];
  const float* ln1w   = (const float*)d_in[7];
  const float* ln1b   = (const float*)d_in[8];
  const float* W2_rel = (const float*)d_in[9];
  const float* b2_rel = (const float*)d_in[10];
  const float* W2_root= (const float*)d_in[11];
  const float* Wp2    = (const float*)d_in[12];
  const float* bp2    = (const float*)d_in[13];
  const float* ln2w   = (const float*)d_in[14];
  const float* ln2b   = (const float*)d_in[15];
  float* out = (float*)d_out;

  int* cnt_dst = (int*)d_ws;                     // NN
  int* cursor  = cnt_dst + NN;                   // NN
  int* bsum    = cursor + NN;                    // 256
  int* csr     = bsum + 256;                     // EE
  float* x1    = (float*)(csr + EE);             // NN*128
  float* s1s   = x1 + (size_t)NN * 128;          // NN*64
  float* dst   = s1s + (size_t)NN * 64;          // 16384 = [px|padj|sts]
  float* px    = dst;
  float* padj  = dst + 8192;
  float* sts   = dst + 12288;
  float* den   = dst + 16384;                    // 4
  float* A1f   = den + 4;                        // 4096
  float* agg2  = A1f + 4096;                     // 8192
  float* x2    = agg2 + 8192;                    // 8192
  float* part2 = x2 + 8192;                      // 32 * 16384
  float* part  = part2 + 32 * 16384;             // nslab * 16384

  // slab count from available workspace (deterministic given ws_size)
  size_t used_floats = (size_t)(part - (float*)d_ws);
  size_t avail = ws_size / 4 - used_floats;
  int nslab = (int)(avail / 16384);
  if (nslab > MAXSLAB) nslab = MAXSLAB;
  if (nslab < 1) nslab = 1;
  int chunk = (nslab + 31) / 32;

  hipMemsetAsync(cnt_dst, 0, NN * sizeof(int), stream);

  k_hist<<<EE / 256, 256, 0, stream>>>(ei, cnt_dst);
  k_scan1<<<NSB, 256, 0, stream>>>(cnt_dst, cursor, bsum);
  k_scan2<<<1, 256, 0, stream>>>(bsum, den);
  k_fill<<<EE / 256, 256, 0, stream>>>(ei, cursor, bsum, csr);
  k_fused1<<<NT32, 256, 0, stream>>>(x, csr, cursor, cnt_dst, bsum,
                                     W1_rel, b1_rel, W1_root, Wp1, bp1,
                                     ln1w, ln1b, x1, out + OUT_S1, s1s);
  k_pooled_all<<<nslab, 256, 0, stream>>>(s1s, x1, csr, cursor, cnt_dst, bsum,
                                          part, den);
  k_reduce1<<<512, 256, 0, stream>>>(part, nslab, chunk, part2);
  k_reduce2<<<64, 256, 0, stream>>>(part2, dst);
  k_p2a<<<1, 256, 0, stream>>>(padj, sts, den, px, out, A1f, agg2);
  k_x2<<<64, 128, 0, stream>>>(agg2, px, W2_rel, b2_rel, W2_root, x2);
  k_p2c<<<1, 256, 0, stream>>>(x2, Wp2, bp2, ln2w, ln2b, A1f, out);
}

// Round 21
// 403.861 us; speedup vs baseline: 1.0191x; 1.0191x over previous
//
#include <hip/hip_runtime.h>

#define NN 50000
#define EE 800000
#define NT32 1563    // ceil(NN/32)
#define NTILE 3125   // NN/16 (pooled tiles)
#define NSB 196      // scan blocks: 196*256 = 50176 >= NN
#define MAXSLAB 1024

#define OUT_S1 4
#define OUT_A1 (4 + NN * 64)
#define OUT_S2 (OUT_A1 + 64 * 64)
#define OUT_ADJ2 (OUT_S2 + 64 * 16)

__device__ __forceinline__ float block_sum256(float v, float* red) {
  v += __shfl_xor(v, 32); v += __shfl_xor(v, 16); v += __shfl_xor(v, 8);
  v += __shfl_xor(v, 4);  v += __shfl_xor(v, 2);  v += __shfl_xor(v, 1);
  __syncthreads();
  if ((threadIdx.x & 63) == 0) red[threadIdx.x >> 6] = v;
  __syncthreads();
  return red[0] + red[1] + red[2] + red[3];
}

// ---- MLP-unrolled gather: sum rows[csr[off..off+c)] (64-float rows),
//      16 lanes per node, lane l holds floats [l*4, l*4+4).
__device__ __forceinline__ float4 gather_rows64(
    const float* __restrict__ rows, const int* __restrict__ csr,
    int off, int c, int l, int g) {
  float4 a0 = make_float4(0.f, 0.f, 0.f, 0.f);
  float4 a1 = a0, a2 = a0, a3 = a0;
  int bb = 0;
  for (; bb + 16 <= c; bb += 16) {
    int myid = csr[off + bb + l];
    #pragma unroll
    for (int j = 0; j < 16; j += 4) {
      int s0 = __shfl(myid, g + j + 0, 64);
      int s1 = __shfl(myid, g + j + 1, 64);
      int s2 = __shfl(myid, g + j + 2, 64);
      int s3 = __shfl(myid, g + j + 3, 64);
      const float4 v0 = *(const float4*)&rows[(size_t)s0 * 64 + l * 4];
      const float4 v1 = *(const float4*)&rows[(size_t)s1 * 64 + l * 4];
      const float4 v2 = *(const float4*)&rows[(size_t)s2 * 64 + l * 4];
      const float4 v3 = *(const float4*)&rows[(size_t)s3 * 64 + l * 4];
      a0.x += v0.x; a0.y += v0.y; a0.z += v0.z; a0.w += v0.w;
      a1.x += v1.x; a1.y += v1.y; a1.z += v1.z; a1.w += v1.w;
      a2.x += v2.x; a2.y += v2.y; a2.z += v2.z; a2.w += v2.w;
      a3.x += v3.x; a3.y += v3.y; a3.z += v3.z; a3.w += v3.w;
    }
  }
  int m = c - bb;
  if (m > 0) {
    int myid = (l < m) ? csr[off + bb + l] : 0;
    int j = 0;
    for (; j + 2 <= m; j += 2) {
      int s0 = __shfl(myid, g + j + 0, 64);
      int s1 = __shfl(myid, g + j + 1, 64);
      const float4 v0 = *(const float4*)&rows[(size_t)s0 * 64 + l * 4];
      const float4 v1 = *(const float4*)&rows[(size_t)s1 * 64 + l * 4];
      a0.x += v0.x; a0.y += v0.y; a0.z += v0.z; a0.w += v0.w;
      a1.x += v1.x; a1.y += v1.y; a1.z += v1.z; a1.w += v1.w;
    }
    if (j < m) {
      int s0 = __shfl(myid, g + j, 64);
      const float4 v0 = *(const float4*)&rows[(size_t)s0 * 64 + l * 4];
      a2.x += v0.x; a2.y += v0.y; a2.z += v0.z; a2.w += v0.w;
    }
  }
  a0.x += a1.x; a0.y += a1.y; a0.z += a1.z; a0.w += a1.w;
  a2.x += a3.x; a2.y += a3.y; a2.z += a3.z; a2.w += a3.w;
  a0.x += a2.x; a0.y += a2.y; a0.z += a2.z; a0.w += a2.w;
  return a0;
}

// ---- gather + sum-of-squares of every loaded element (for mincut_den)
__device__ __forceinline__ float4 gather_rows64_sq(
    const float* __restrict__ rows, const int* __restrict__ csr,
    int off, int c, int l, int g, float& dsq) {
  float4 a0 = make_float4(0.f, 0.f, 0.f, 0.f);
  float4 a1 = a0, a2 = a0, a3 = a0;
  int bb = 0;
  for (; bb + 16 <= c; bb += 16) {
    int myid = csr[off + bb + l];
    #pragma unroll
    for (int j = 0; j < 16; j += 4) {
      int s0 = __shfl(myid, g + j + 0, 64);
      int s1 = __shfl(myid, g + j + 1, 64);
      int s2 = __shfl(myid, g + j + 2, 64);
      int s3 = __shfl(myid, g + j + 3, 64);
      const float4 v0 = *(const float4*)&rows[(size_t)s0 * 64 + l * 4];
      const float4 v1 = *(const float4*)&rows[(size_t)s1 * 64 + l * 4];
      const float4 v2 = *(const float4*)&rows[(size_t)s2 * 64 + l * 4];
      const float4 v3 = *(const float4*)&rows[(size_t)s3 * 64 + l * 4];
      a0.x += v0.x; a0.y += v0.y; a0.z += v0.z; a0.w += v0.w;
      a1.x += v1.x; a1.y += v1.y; a1.z += v1.z; a1.w += v1.w;
      a2.x += v2.x; a2.y += v2.y; a2.z += v2.z; a2.w += v2.w;
      a3.x += v3.x; a3.y += v3.y; a3.z += v3.z; a3.w += v3.w;
      dsq += v0.x * v0.x + v0.y * v0.y + v0.z * v0.z + v0.w * v0.w;
      dsq += v1.x * v1.x + v1.y * v1.y + v1.z * v1.z + v1.w * v1.w;
      dsq += v2.x * v2.x + v2.y * v2.y + v2.z * v2.z + v2.w * v2.w;
      dsq += v3.x * v3.x + v3.y * v3.y + v3.z * v3.z + v3.w * v3.w;
    }
  }
  int m = c - bb;
  if (m > 0) {
    int myid = (l < m) ? csr[off + bb + l] : 0;
    int j = 0;
    for (; j + 2 <= m; j += 2) {
      int s0 = __shfl(myid, g + j + 0, 64);
      int s1 = __shfl(myid, g + j + 1, 64);
      const float4 v0 = *(const float4*)&rows[(size_t)s0 * 64 + l * 4];
      const float4 v1 = *(const float4*)&rows[(size_t)s1 * 64 + l * 4];
      a0.x += v0.x; a0.y += v0.y; a0.z += v0.z; a0.w += v0.w;
      a1.x += v1.x; a1.y += v1.y; a1.z += v1.z; a1.w += v1.w;
      dsq += v0.x * v0.x + v0.y * v0.y + v0.z * v0.z + v0.w * v0.w;
      dsq += v1.x * v1.x + v1.y * v1.y + v1.z * v1.z + v1.w * v1.w;
    }
    if (j < m) {
      int s0 = __shfl(myid, g + j, 64);
      const float4 v0 = *(const float4*)&rows[(size_t)s0 * 64 + l * 4];
      a2.x += v0.x; a2.y += v0.y; a2.z += v0.z; a2.w += v0.w;
      dsq += v0.x * v0.x + v0.y * v0.y + v0.z * v0.z + v0.w * v0.w;
    }
  }
  a0.x += a1.x; a0.y += a1.y; a0.z += a1.z; a0.w += a1.w;
  a2.x += a3.x; a2.y += a3.y; a2.z += a3.z; a2.w += a3.w;
  a0.x += a2.x; a0.y += a2.y; a0.z += a2.z; a0.w += a2.w;
  return a0;
}

// ---- H: histogram in-degree (by dst, for CSR) only
__global__ __launch_bounds__(256) void k_hist(
    const int* __restrict__ ei, int* __restrict__ cnt_dst) {
  int e = blockIdx.x * 256 + threadIdx.x;
  int d = ei[EE + e];
  atomicAdd(&cnt_dst[d], 1);
}

// ---- Scan stage 1: per-block exclusive scan -> cursor (local), block sums
__global__ __launch_bounds__(256) void k_scan1(
    const int* __restrict__ cnt, int* __restrict__ cursor, int* __restrict__ bsum) {
  __shared__ int sh[256];
  int t = threadIdx.x;
  int idx = blockIdx.x * 256 + t;
  int v = (idx < NN) ? cnt[idx] : 0;
  sh[t] = v;
  __syncthreads();
  for (int o = 1; o < 256; o <<= 1) {
    int u = (t >= o) ? sh[t - o] : 0;
    __syncthreads();
    sh[t] += u;
    __syncthreads();
  }
  if (idx < NN) cursor[idx] = sh[t] - v;
  if (t == 255) bsum[blockIdx.x] = sh[255];
}

// ---- Scan stage 2: exclusive scan of block sums (1 block); also zero den
__global__ __launch_bounds__(256) void k_scan2(
    int* __restrict__ bsum, float* __restrict__ den) {
  __shared__ int sh[256];
  int t = threadIdx.x;
  int v = (t < NSB) ? bsum[t] : 0;
  sh[t] = v;
  __syncthreads();
  for (int o = 1; o < 256; o <<= 1) {
    int u = (t >= o) ? sh[t - o] : 0;
    __syncthreads();
    sh[t] += u;
    __syncthreads();
  }
  if (t < NSB) bsum[t] = sh[t] - v;
  if (t == 0) den[0] = 0.f;
}

// ---- F: fill CSR (cursor holds LOCAL prefix; add bsum inline).
__global__ __launch_bounds__(256) void k_fill(
    const int* __restrict__ ei, int* __restrict__ cursor,
    const int* __restrict__ bsum, int* __restrict__ csr) {
  int e = blockIdx.x * 256 + threadIdx.x;
  int s = ei[e], d = ei[EE + e];
  int pos = atomicAdd(&cursor[d], 1) + bsum[d >> 8];
  csr[pos] = s;
}

// ---- FUSED1 (32-node tiles, LDS-union):
//      A: gather agg + stage x; B: x1 (regs) -> global + smem; C: s1 LN+softmax.
__global__ __launch_bounds__(256, 4) void k_fused1(
    const float* __restrict__ x, const int* __restrict__ csr,
    const int* __restrict__ cur_end, const int* __restrict__ cnt,
    const int* __restrict__ bsum,
    const float* __restrict__ W1rel, const float* __restrict__ b1,
    const float* __restrict__ W1root,
    const float* __restrict__ Wp1, const float* __restrict__ bp1,
    const float* __restrict__ lnw, const float* __restrict__ lnb,
    float* __restrict__ x1, float* __restrict__ s1_out,
    float* __restrict__ s1s) {
  __shared__ float smem[4224];   // A/B: agg=[0,2048) x=[2048,4096); C: x1 32x132
  float* agg_t = smem;
  float* x_t   = smem + 2048;
  float* x1_t  = smem;           // [n][k] at n*132+k (padded rows)
  int t = threadIdx.x;
  int base = blockIdx.x * 32;

  // ---- Phase A
  {
    int n16 = t >> 4, l = t & 15;
    #pragma unroll
    for (int half = 0; half < 2; ++half) {
      int n = n16 + half * 16;
      int node = base + n;
      if (node < NN) {
        *(float4*)&x_t[n * 64 + l * 4] = *(const float4*)&x[(size_t)node * 64 + l * 4];
        int c = cnt[node];
        int off = cur_end[node] - c + bsum[node >> 8];
        float4 acc = gather_rows64(x, csr, off, c, l, t & 48);
        *(float4*)&agg_t[n * 64 + l * 4] = acc;
      } else {
        float4 z = make_float4(0.f, 0.f, 0.f, 0.f);
        *(float4*)&x_t[n * 64 + l * 4] = z;
        *(float4*)&agg_t[n * 64 + l * 4] = z;
      }
    }
  }
  __syncthreads();

  // ---- Phase B: x1 tile in registers. thread = 4 rows x 4 cols.
  int rg = t >> 5, cg = t & 31;
  int r0 = rg * 4;
  int c4 = cg * 4;
  float4 r0v, r1v, r2v, r3v;
  {
    float4 acc0 = *(const float4*)&b1[c4];
    float4 acc1 = acc0, acc2 = acc0, acc3 = acc0;
    #pragma unroll 4
    for (int k = 0; k < 64; ++k) {
      const float4 w1 = *(const float4*)&W1rel[k * 128 + c4];
      const float4 w2 = *(const float4*)&W1root[k * 128 + c4];
      float a0 = agg_t[(r0 + 0) * 64 + k], e0 = x_t[(r0 + 0) * 64 + k];
      float a1 = agg_t[(r0 + 1) * 64 + k], e1 = x_t[(r0 + 1) * 64 + k];
      float a2 = agg_t[(r0 + 2) * 64 + k], e2 = x_t[(r0 + 2) * 64 + k];
      float a3 = agg_t[(r0 + 3) * 64 + k], e3 = x_t[(r0 + 3) * 64 + k];
      acc0.x += a0 * w1.x + e0 * w2.x; acc0.y += a0 * w1.y + e0 * w2.y;
      acc0.z += a0 * w1.z + e0 * w2.z; acc0.w += a0 * w1.w + e0 * w2.w;
      acc1.x += a1 * w1.x + e1 * w2.x; acc1.y += a1 * w1.y + e1 * w2.y;
      acc1.z += a1 * w1.z + e1 * w2.z; acc1.w += a1 * w1.w + e1 * w2.w;
      acc2.x += a2 * w1.x + e2 * w2.x; acc2.y += a2 * w1.y + e2 * w2.y;
      acc2.z += a2 * w1.z + e2 * w2.z; acc2.w += a2 * w1.w + e2 * w2.w;
      acc3.x += a3 * w1.x + e3 * w2.x; acc3.y += a3 * w1.y + e3 * w2.y;
      acc3.z += a3 * w1.z + e3 * w2.z; acc3.w += a3 * w1.w + e3 * w2.w;
    }
    r0v.x = fmaxf(acc0.x, 0.f); r0v.y = fmaxf(acc0.y, 0.f);
    r0v.z = fmaxf(acc0.z, 0.f); r0v.w = fmaxf(acc0.w, 0.f);
    r1v.x = fmaxf(acc1.x, 0.f); r1v.y = fmaxf(acc1.y, 0.f);
    r1v.z = fmaxf(acc1.z, 0.f); r1v.w = fmaxf(acc1.w, 0.f);
    r2v.x = fmaxf(acc2.x, 0.f); r2v.y = fmaxf(acc2.y, 0.f);
    r2v.z = fmaxf(acc2.z, 0.f); r2v.w = fmaxf(acc2.w, 0.f);
    r3v.x = fmaxf(acc3.x, 0.f); r3v.y = fmaxf(acc3.y, 0.f);
    r3v.z = fmaxf(acc3.z, 0.f); r3v.w = fmaxf(acc3.w, 0.f);
    if (base + r0 + 3 < NN) {
      *(float4*)&x1[(size_t)(base + r0 + 0) * 128 + c4] = r0v;
      *(float4*)&x1[(size_t)(base + r0 + 1) * 128 + c4] = r1v;
      *(float4*)&x1[(size_t)(base + r0 + 2) * 128 + c4] = r2v;
      *(float4*)&x1[(size_t)(base + r0 + 3) * 128 + c4] = r3v;
    } else {
      if (base + r0 + 0 < NN) *(float4*)&x1[(size_t)(base + r0 + 0) * 128 + c4] = r0v;
      if (base + r0 + 1 < NN) *(float4*)&x1[(size_t)(base + r0 + 1) * 128 + c4] = r1v;
      if (base + r0 + 2 < NN) *(float4*)&x1[(size_t)(base + r0 + 2) * 128 + c4] = r2v;
    }
  }
  __syncthreads();  // all reads of agg_t/x_t complete
  *(float4*)&x1_t[(r0 + 0) * 132 + c4] = r0v;
  *(float4*)&x1_t[(r0 + 1) * 132 + c4] = r1v;
  *(float4*)&x1_t[(r0 + 2) * 132 + c4] = r2v;
  *(float4*)&x1_t[(r0 + 3) * 132 + c4] = r3v;
  __syncthreads();

  // ---- Phase C: thread = 4 rows x 2 cols, k-blocked x4, unroll pinned.
  {
    int c2 = cg * 2;
    const float2 b0 = *(const float2*)&bp1[c2];
    float2 acc0 = b0, acc1 = b0, acc2 = b0, acc3 = b0;
    #pragma unroll 4
    for (int k0 = 0; k0 < 128; k0 += 4) {
      const float2 w0 = *(const float2*)&Wp1[(k0 + 0) * 64 + c2];
      const float2 w1 = *(const float2*)&Wp1[(k0 + 1) * 64 + c2];
      const float2 w2 = *(const float2*)&Wp1[(k0 + 2) * 64 + c2];
      const float2 w3 = *(const float2*)&Wp1[(k0 + 3) * 64 + c2];
      const float4 x0 = *(const float4*)&x1_t[(r0 + 0) * 132 + k0];
      const float4 x1v = *(const float4*)&x1_t[(r0 + 1) * 132 + k0];
      const float4 x2v = *(const float4*)&x1_t[(r0 + 2) * 132 + k0];
      const float4 x3v = *(const float4*)&x1_t[(r0 + 3) * 132 + k0];
      acc0.x += x0.x * w0.x + x0.y * w1.x + x0.z * w2.x + x0.w * w3.x;
      acc0.y += x0.x * w0.y + x0.y * w1.y + x0.z * w2.y + x0.w * w3.y;
      acc1.x += x1v.x * w0.x + x1v.y * w1.x + x1v.z * w2.x + x1v.w * w3.x;
      acc1.y += x1v.x * w0.y + x1v.y * w1.y + x1v.z * w2.y + x1v.w * w3.y;
      acc2.x += x2v.x * w0.x + x2v.y * w1.x + x2v.z * w2.x + x2v.w * w3.x;
      acc2.y += x2v.x * w0.y + x2v.y * w1.y + x2v.z * w2.y + x2v.w * w3.y;
      acc3.x += x3v.x * w0.x + x3v.y * w1.x + x3v.z * w2.x + x3v.w * w3.x;
      acc3.y += x3v.x * w0.y + x3v.y * w1.y + x3v.z * w2.y + x3v.w * w3.y;
    }
    const float2 lw = *(const float2*)&lnw[c2];
    const float2 lb = *(const float2*)&lnb[c2];
    float2 accs[4] = {acc0, acc1, acc2, acc3};
    #pragma unroll
    for (int i = 0; i < 4; ++i) {
      int row = base + r0 + i;
      float ax = accs[i].x, ay = accs[i].y;
      float m = ax + ay;
      m += __shfl_xor(m, 1); m += __shfl_xor(m, 2); m += __shfl_xor(m, 4);
      m += __shfl_xor(m, 8); m += __shfl_xor(m, 16);
      m *= (1.0f / 64.0f);
      float dx = ax - m, dy = ay - m;
      float v = dx * dx + dy * dy;
      v += __shfl_xor(v, 1); v += __shfl_xor(v, 2); v += __shfl_xor(v, 4);
      v += __shfl_xor(v, 8); v += __shfl_xor(v, 16);
      v *= (1.0f / 64.0f);
      float rstd = rsqrtf(v + 1e-5f);
      float lnx = dx * rstd * lw.x + lb.x;
      float lny = dy * rstd * lw.y + lb.y;
      float mx = fmaxf(lnx, lny);
      mx = fmaxf(mx, __shfl_xor(mx, 1)); mx = fmaxf(mx, __shfl_xor(mx, 2));
      mx = fmaxf(mx, __shfl_xor(mx, 4)); mx = fmaxf(mx, __shfl_xor(mx, 8));
      mx = fmaxf(mx, __shfl_xor(mx, 16));
      float ex = expf(lnx - mx), ey = expf(lny - mx);
      float se = ex + ey;
      se += __shfl_xor(se, 1); se += __shfl_xor(se, 2); se += __shfl_xor(se, 4);
      se += __shfl_xor(se, 8); se += __shfl_xor(se, 16);
      float inv = 1.0f / se;
      ex *= inv; ey *= inv;
      if (row < NN) {
        *(float2*)&s1_out[(size_t)row * 64 + c2] = make_float2(lnx, lny);
        *(float2*)&s1s[(size_t)row * 64 + c2] = make_float2(ex, ey);
      }
    }
  }
}

// ---- POOLED_ALL: per 16-node tile (grid-stride): stage s,x1; gather G (+den);
//      px += s.T@x1, padj += G.T@s, sts += s.T@s. Slab: [px 8192|padj 4096|sts 4096]
__global__ __launch_bounds__(256, 4) void k_pooled_all(
    const float* __restrict__ s1s, const float* __restrict__ x1,
    const int* __restrict__ csr, const int* __restrict__ cur_end,
    const int* __restrict__ cnt, const int* __restrict__ bsum,
    float* __restrict__ part, float* __restrict__ den) {
  __shared__ float s_t[1024];   // 16 x 64
  __shared__ float g_t[1024];   // 16 x 64
  __shared__ float x_t[2048];   // 16 x 128
  __shared__ float red[4];
  int t = threadIdx.x;
  int kg = t >> 5;              // 0..7 : k = kg*8 + j
  int cg = t & 31;              // 0..31
  int c1 = cg * 4;              // x cols
  int cc = (cg & 15) * 4;       // s cols (padj for cg<16, sts for cg>=16)
  bool is_padj = (cg < 16);
  float a1[8][4], a2[8][4];
  float dsq = 0.f;
  #pragma unroll
  for (int j = 0; j < 8; ++j)
    #pragma unroll
    for (int q = 0; q < 4; ++q) { a1[j][q] = 0.f; a2[j][q] = 0.f; }

  for (int tile = blockIdx.x; tile < NTILE; tile += gridDim.x) {
    size_t base = (size_t)tile * 16;
    __syncthreads();
    *(float4*)&s_t[t * 4] = *(const float4*)&s1s[base * 64 + t * 4];
    *(float4*)&x_t[t * 8] = *(const float4*)&x1[base * 128 + t * 8];
    *(float4*)&x_t[t * 8 + 4] = *(const float4*)&x1[base * 128 + t * 8 + 4];
    {
      int n16 = t >> 4, l = t & 15;
      int node = (int)base + n16;
      int c = cnt[node];
      int off = cur_end[node] - c + bsum[node >> 8];
      float4 acc = gather_rows64_sq(s1s, csr, off, c, l, t & 48, dsq);
      *(float4*)&g_t[n16 * 64 + l * 4] = acc;
    }
    __syncthreads();
    #pragma unroll 2
    for (int r = 0; r < 16; ++r) {
      const float4 xv = *(const float4*)&x_t[r * 128 + c1];
      const float4 sv = *(const float4*)&s_t[r * 64 + cc];
      const float4 k0 = *(const float4*)&s_t[r * 64 + kg * 8];
      const float4 k1 = *(const float4*)&s_t[r * 64 + kg * 8 + 4];
      const float4 g0 = *(const float4*)&g_t[r * 64 + kg * 8];
      const float4 g1 = *(const float4*)&g_t[r * 64 + kg * 8 + 4];
      float sk[8] = {k0.x, k0.y, k0.z, k0.w, k1.x, k1.y, k1.z, k1.w};
      float gk[8] = {g0.x, g0.y, g0.z, g0.w, g1.x, g1.y, g1.z, g1.w};
      #pragma unroll
      for (int j = 0; j < 8; ++j) {
        float m2 = is_padj ? gk[j] : sk[j];
        a1[j][0] += sk[j] * xv.x; a1[j][1] += sk[j] * xv.y;
        a1[j][2] += sk[j] * xv.z; a1[j][3] += sk[j] * xv.w;
        a2[j][0] += m2 * sv.x; a2[j][1] += m2 * sv.y;
        a2[j][2] += m2 * sv.z; a2[j][3] += m2 * sv.w;
      }
    }
  }
  float* slab = part + (size_t)blockIdx.x * 16384;
  float* o2base = slab + (is_padj ? 8192 : 12288);
  #pragma unroll
  for (int j = 0; j < 8; ++j) {
    int k = kg * 8 + j;
    *(float4*)&slab[k * 128 + c1] = make_float4(a1[j][0], a1[j][1], a1[j][2], a1[j][3]);
    *(float4*)&o2base[k * 64 + cc] = make_float4(a2[j][0], a2[j][1], a2[j][2], a2[j][3]);
  }
  float dtot = block_sum256(dsq, red);
  if (t == 0) atomicAdd(den, dtot);
}

// ---- R1: partial-reduce slabs. grid = 16 i-blocks x 32 slab-groups.
__global__ __launch_bounds__(256) void k_reduce1(
    const float* __restrict__ part, int nslab, int chunk,
    float* __restrict__ part2) {
  int ib = blockIdx.x & 15;
  int bs = blockIdx.x >> 4;              // 0..31
  int i4 = ib * 256 + threadIdx.x;       // float4 index 0..4095
  int b0 = bs * chunk;
  int b1 = b0 + chunk; if (b1 > nslab) b1 = nslab;
  float4 acc = make_float4(0.f, 0.f, 0.f, 0.f);
  for (int b = b0; b < b1; ++b) {
    const float4 v = *(const float4*)&part[(size_t)b * 16384 + (size_t)i4 * 4];
    acc.x += v.x; acc.y += v.y; acc.z += v.z; acc.w += v.w;
  }
  *(float4*)&part2[(size_t)bs * 16384 + (size_t)i4 * 4] = acc;
}

// ---- R2: final reduce of 32 partials -> dst = [px 8192 | padj 4096 | sts 4096]
__global__ __launch_bounds__(256) void k_reduce2(
    const float* __restrict__ part2, float* __restrict__ dst) {
  int i = blockIdx.x * 256 + threadIdx.x;  // 0..16383
  float acc = 0.f;
  #pragma unroll
  for (int b = 0; b < 32; ++b) acc += part2[b * 16384 + i];
  dst[i] = acc;
}

// ---- P2a: mc1, o1, A1, agg2 = A1.T @ pooled_x
__global__ __launch_bounds__(256) void k_p2a(
    const float* __restrict__ padj_g, const float* __restrict__ sts_g,
    const float* __restrict__ den_g, const float* __restrict__ px_g,
    float* __restrict__ out, float* __restrict__ A1f, float* __restrict__ agg2) {
  __shared__ float padj[4096];
  __shared__ float A1s[4096];
  __shared__ float invs[64];
  __shared__ float red[4];
  int t = threadIdx.x;
  for (int i = t; i < 4096; i += 256) padj[i] = padj_g[i];
  __syncthreads();
  float num = (t < 64) ? padj[t * 64 + t] : 0.f;
  num = block_sum256(num, red);
  float n2 = 0.f;
  for (int i = t; i < 4096; i += 256) { float v = sts_g[i]; n2 += v * v; }
  n2 = block_sum256(n2, red);
  float nrm = sqrtf(n2);
  float oacc = 0.f;
  for (int i = t; i < 4096; i += 256) {
    float v = sts_g[i] / (nrm + 1e-10f);
    if ((i >> 6) == (i & 63)) v -= 0.125f;  // 1/sqrt(64)
    oacc += v * v;
  }
  oacc = block_sum256(oacc, red);
  if (t == 0) {
    out[0] = -num / (den_g[0] + 1e-10f);
    out[1] = sqrtf(oacc);
  }
  if (t < 64) {
    float rs = 0.f;
    for (int j = 0; j < 64; ++j)
      if (j != t) rs += padj[t * 64 + j];
    invs[t] = 1.0f / (sqrtf(rs) + 1e-15f);
  }
  __syncthreads();
  const float THRv = 1.0f / 63.0f;
  for (int i = t; i < 4096; i += 256) {
    int r = i >> 6, c = i & 63;
    float a = (r == c) ? 0.f : padj[i] * invs[r] * invs[c];
    float b = (a > THRv) ? 1.0f : 0.0f;
    out[OUT_A1 + i] = b;
    A1f[i] = b;
    A1s[i] = b;
  }
  __syncthreads();
  int j = t >> 2, q = t & 3;
  float acc[32];
  #pragma unroll
  for (int c = 0; c < 32; ++c) acc[c] = 0.f;
  for (int i = 0; i < 64; ++i) {
    float a = A1s[i * 64 + j];
    const float* pxr = px_g + i * 128 + q * 32;
    #pragma unroll
    for (int c = 0; c < 32; ++c) acc[c] += a * pxr[c];
  }
  #pragma unroll
  for (int c = 0; c < 32; ++c) agg2[j * 128 + q * 32 + c] = acc[c];
}

// ---- P2b: x2 = relu(agg2 @ W2_rel + b2 + pooled_x @ W2_root)
__global__ __launch_bounds__(128) void k_x2(
    const float* __restrict__ agg2, const float* __restrict__ px,
    const float* __restrict__ W2rel, const float* __restrict__ b2,
    const float* __restrict__ W2root, float* __restrict__ x2) {
  int row = blockIdx.x, col = threadIdx.x;
  const float* ar = agg2 + row * 128;
  const float* xr = px + row * 128;
  float acc = b2[col];
  #pragma unroll 4
  for (int k = 0; k < 128; ++k)
    acc += ar[k] * W2rel[k * 128 + col] + xr[k] * W2root[k * 128 + col];
  x2[row * 128 + col] = fmaxf(acc, 0.f);
}

// ---- P2c: s2 (LN), softmax, A_s2, mincut2, adj2
__global__ __launch_bounds__(256) void k_p2c(
    const float* __restrict__ x2g, const float* __restrict__ Wp2,
    const float* __restrict__ bp2, const float* __restrict__ lnw,
    const float* __restrict__ lnb, const float* __restrict__ A1f,
    float* __restrict__ out) {
  __shared__ float A1s[4096];
  __shared__ float s2lin[1024];
  __shared__ float s2s[1024];
  __shared__ float As2[1024];
  __shared__ float deg2[64];
  __shared__ float padj2[256];
  __shared__ float sts2[256];
  __shared__ float inv2[16];
  __shared__ float red[4];
  int t = threadIdx.x;
  for (int i = t; i < 4096; i += 256) A1s[i] = A1f[i];
  for (int it = 0; it < 4; ++it) {
    int idx = t + it * 256;
    int r = idx >> 4, c = idx & 15;
    float acc = bp2[c];
    const float* xr = x2g + r * 128;
    #pragma unroll 8
    for (int k = 0; k < 128; ++k) acc += xr[k] * Wp2[k * 16 + c];
    s2lin[idx] = acc;
  }
  __syncthreads();
  if (t < 64) {
    float m = 0.f;
    #pragma unroll
    for (int c = 0; c < 16; ++c) m += s2lin[t * 16 + c];
    m *= (1.0f / 16.0f);
    float v = 0.f;
    #pragma unroll
    for (int c = 0; c < 16; ++c) { float d = s2lin[t * 16 + c] - m; v += d * d; }
    v *= (1.0f / 16.0f);
    float rstd = rsqrtf(v + 1e-5f);
    float mx = -1e30f;
    float lnv[16];
    #pragma unroll
    for (int c = 0; c < 16; ++c) {
      lnv[c] = (s2lin[t * 16 + c] - m) * rstd * lnw[c] + lnb[c];
      out[OUT_S2 + t * 16 + c] = lnv[c];
      mx = fmaxf(mx, lnv[c]);
    }
    float se = 0.f;
    #pragma unroll
    for (int c = 0; c < 16; ++c) { float e = expf(lnv[c] - mx); s2s[t * 16 + c] = e; se += e; }
    float inv = 1.0f / se;
    #pragma unroll
    for (int c = 0; c < 16; ++c) s2s[t * 16 + c] *= inv;
    float dg = 0.f;
    for (int j = 0; j < 64; ++j) dg += A1s[t * 64 + j];
    deg2[t] = dg;
  }
  __syncthreads();
  for (int it = 0; it < 4; ++it) {
    int idx = t + it * 256;
    int i = idx >> 4, c = idx & 15;
    float acc = 0.f;
    for (int j = 0; j < 64; ++j) acc += A1s[i * 64 + j] * s2s[j * 16 + c];
    As2[idx] = acc;
  }
  __syncthreads();
  {
    int a = t >> 4, b = t & 15;
    float acc = 0.f, accs = 0.f;
    for (int i = 0; i < 64; ++i) {
      float sa = s2s[i * 16 + a];
      acc += sa * As2[i * 16 + b];
      accs += sa * s2s[i * 16 + b];
    }
    padj2[t] = acc;
    sts2[t] = accs;
  }
  __syncthreads();
  float num2 = (t < 16) ? padj2[t * 17] : 0.f;
  num2 = block_sum256(num2, red);
  float dpart = 0.f;
  if (t < 64) {
    float ss = 0.f;
    #pragma unroll
    for (int c = 0; c < 16; ++c) ss += s2s[t * 16 + c] * s2s[t * 16 + c];
    dpart = deg2[t] * ss;
  }
  float den2 = block_sum256(dpart, red);
  float n2 = sts2[t] * sts2[t];
  n2 = block_sum256(n2, red);
  float nrm2 = sqrtf(n2);
  float ov;
  {
    float v = sts2[t] / (nrm2 + 1e-10f);
    if ((t >> 4) == (t & 15)) v -= 0.25f;  // 1/sqrt(16)
    ov = v * v;
  }
  ov = block_sum256(ov, red);
  if (t == 0) {
    out[2] = -num2 / (den2 + 1e-10f);
    out[3] = sqrtf(ov);
  }
  if (t < 16) {
    float rs = 0.f;
    #pragma unroll
    for (int b = 0; b < 16; ++b)
      if (b != t) rs += padj2[t * 16 + b];
    inv2[t] = 1.0f / (sqrtf(rs) + 1e-15f);
  }
  __syncthreads();
  {
    int a = t >> 4, b = t & 15;
    float v = (a == b) ? 0.f : padj2[t] * inv2[a] * inv2[b];
    out[OUT_ADJ2 + t] = v;
  }
}

extern "C" void kernel_launch(void* const* d_in, const int* in_sizes, int n_in,
                              void* d_out, int out_size, void* d_ws, size_t ws_size,
                              hipStream_t stream) {
  const float* x      = (const float*)d_in[0];
  const int*   ei     = (const int*)d_in[1];
  const float* W1_rel = (const float*)d_in[2];
  const float* b1_rel = (const float*)d_in[3];
  const float* W1_root= (const float*)d_in[4];
  const float* Wp1    = (const float*)d_in[5];
  const float* bp1    = (const float*)d_in[6];
  const float* ln1w   = (const float*)d_in[7];
  const float* ln1b   = (const float*)d_in[8];
  const float* W2_rel = (const float*)d_in[9];
  const float* b2_rel = (const float*)d_in[10];
  const float* W2_root= (const float*)d_in[11];
  const float* Wp2    = (const float*)d_in[12];
  const float* bp2    = (const float*)d_in[13];
  const float* ln2w   = (const float*)d_in[14];
  const float* ln2b   = (const float*)d_in[15];
  float* out = (float*)d_out;

  int* cnt_dst = (int*)d_ws;                     // NN
  int* cursor  = cnt_dst + NN;                   // NN
  int* bsum    = cursor + NN;                    // 256
  int* csr     = bsum + 256;                     // EE
  float* x1    = (float*)(csr + EE);             // NN*128
  float* s1s   = x1 + (size_t)NN * 128;          // NN*64
  float* dst   = s1s + (size_t)NN * 64;          // 16384 = [px|padj|sts]
  float* px    = dst;
  float* padj  = dst + 8192;
  float* sts   = dst + 12288;
  float* den   = dst + 16384;                    // 4
  float* A1f   = den + 4;                        // 4096
  float* agg2  = A1f + 4096;                     // 8192
  float* x2    = agg2 + 8192;                    // 8192
  float* part2 = x2 + 8192;                      // 32 * 16384
  float* part  = part2 + 32 * 16384;             // nslab * 16384

  // slab count from available workspace (deterministic given ws_size)
  size_t used_floats = (size_t)(part - (float*)d_ws);
  size_t avail = ws_size / 4 - used_floats;
  int nslab = (int)(avail / 16384);
  if (nslab > MAXSLAB) nslab = MAXSLAB;
  if (nslab < 1) nslab = 1;
  int chunk = (nslab + 31) / 32;

  hipMemsetAsync(cnt_dst, 0, NN * sizeof(int), stream);

  k_hist<<<EE / 256, 256, 0, stream>>>(ei, cnt_dst);
  k_scan1<<<NSB, 256, 0, stream>>>(cnt_dst, cursor, bsum);
  k_scan2<<<1, 256, 0, stream>>>(bsum, den);
  k_fill<<<EE / 256, 256, 0, stream>>>(ei, cursor, bsum, csr);
  k_fused1<<<NT32, 256, 0, stream>>>(x, csr, cursor, cnt_dst, bsum,
                                     W1_rel, b1_rel, W1_root, Wp1, bp1,
                                     ln1w, ln1b, x1, out + OUT_S1, s1s);
  k_pooled_all<<<nslab, 256, 0, stream>>>(s1s, x1, csr, cursor, cnt_dst, bsum,
                                          part, den);
  k_reduce1<<<512, 256, 0, stream>>>(part, nslab, chunk, part2);
  k_reduce2<<<64, 256, 0, stream>>>(part2, dst);
  k_p2a<<<1, 256, 0, stream>>>(padj, sts, den, px, out, A1f, agg2);
  k_x2<<<64, 128, 0, stream>>>(agg2, px, W2_rel, b2_rel, W2_root, x2);
  k_p2c<<<1, 256, 0, stream>>>(x2, Wp2, bp2, ln2w, ln2b, A1f, out);
}